// Round 16
// baseline (115.787 us; speedup 1.0000x reference)
//
#include <hip/hip_runtime.h>
#include <hip/hip_bf16.h>

// CausalSelfAttention quirk kernel: softmax over QUERY axis, scale sqrt(D_OUT)=32.
// w[q,k] = exp(S/32)/Z[k], Z[k] = sum_{q>=k} exp(S/32)  (per-COLUMN denominator).
// Pass A (k_cstat) computes Z and folds 1/Z into V; pass B (k_ctx) recomputes S
// tile-wise and does PV. 1/32*log2e folded into Q at the QKV epilogue.
// Round 16: k_ctx EQUAL-LENGTH pairing. r13's gain = 2 co-resident independent
// blocks/CU filling each other's bubbles; big+small pairing killed the partner
// after ~1 iter -> solo-aligned regime for ~90% of the big block's life. Now
// blocks i and i+256 (which co-locate at exactly 2 blocks/CU) share the SAME tb
// (different bh) so both live the full duration. tb-major descending dispatch.

typedef __attribute__((ext_vector_type(8))) short short8;
typedef __attribute__((ext_vector_type(4))) float floatx4;
typedef __attribute__((ext_vector_type(16))) float floatx16;

#define SS 2048
#define DIN 1024
#define DOUT 1024
#define NH 16
#define HD 64
#define QSCALE 0.04508422002778011f  // (1/32) * log2(e)

#define MFMA16(a,b,c) __builtin_amdgcn_mfma_f32_16x16x32_bf16((a),(b),(c),0,0,0)
#define MFMA32(a,b,c) __builtin_amdgcn_mfma_f32_32x32x16_bf16((a),(b),(c),0,0,0)
#define EXP2F(x) __builtin_amdgcn_exp2f(x)
#define SBAR() __builtin_amdgcn_s_barrier()
#define WAITV0() asm volatile("s_waitcnt vmcnt(0)" ::: "memory")
#define WAITV4() asm volatile("s_waitcnt vmcnt(4)" ::: "memory")
#define WAITV8() asm volatile("s_waitcnt vmcnt(8)" ::: "memory")

__device__ __forceinline__ void gl_lds16(const void* g, void* l) {
  __builtin_amdgcn_global_load_lds((const __attribute__((address_space(1))) void*)g,
                                   (__attribute__((address_space(3))) void*)l, 16, 0, 0);
}

// Stage an 8-row chunk `c` of a [*][64] bf16 tile (global row stride `stride` elems)
// into LDS at lds + c*512, linear dest. XOR-swizzle applied on the GLOBAL source
// slot so that LDS[r][slot s] holds global slot s^(r&7).
__device__ __forceinline__ void stage64(const __hip_bfloat16* __restrict__ src, int stride,
                                        __hip_bfloat16* lds, int c, int l) {
  int r = c * 8 + (l >> 3);
  int cc = ((l & 7) ^ ((l >> 3) & 7)) * 8;
  gl_lds16(src + (size_t)r * stride + cc, lds + c * 512);
}

// 16x16x32 fragment from a [*][64] swizzled tile: row `row`, k-slot ks*4+(l>>4).
__device__ __forceinline__ short8 frag64(const __hip_bfloat16* lds, int row, int ks, int l) {
  return *(const short8*)&lds[row * 64 + (((ks * 4 + (l >> 4)) ^ (row & 7)) * 8)];
}

// 32x32x16 fragment: row `row` (0..63), 16-wide k-chunk `subk` (0..3), elems
// k = subk*16 + (l>>5)*8 + 0..7.
__device__ __forceinline__ short8 frag32(const __hip_bfloat16* lds, int row, int subk, int l) {
  return *(const short8*)&lds[row * 64 + (((subk * 2 + (l >> 5)) ^ (row & 7)) * 8)];
}

// ---- convert x fp32 -> bf16 ----
__global__ __launch_bounds__(256) void k_cvt_x(const float* __restrict__ x,
                                               __hip_bfloat16* __restrict__ xb) {
  size_t i = ((size_t)blockIdx.x * 256 + threadIdx.x) * 4;
  float4 v = *(const float4*)(x + i);
  union { __hip_bfloat16 h[4]; short4 s; } u;
  u.h[0] = __float2bfloat16(v.x); u.h[1] = __float2bfloat16(v.y);
  u.h[2] = __float2bfloat16(v.z); u.h[3] = __float2bfloat16(v.w);
  *(short4*)(xb + i) = u.s;
}

// ---- transpose + convert W [k][c] fp32 -> Wt [c][k] bf16; z selects Q/K/V ----
__global__ void k_twb(const float* __restrict__ Wq, const float* __restrict__ Wk,
                      const float* __restrict__ Wv,
                      __hip_bfloat16* __restrict__ wtq, __hip_bfloat16* __restrict__ wtk,
                      __hip_bfloat16* __restrict__ wtv) {
  const float* W; __hip_bfloat16* Wt;
  if (blockIdx.z == 0)      { W = Wq; Wt = wtq; }
  else if (blockIdx.z == 1) { W = Wk; Wt = wtk; }
  else                      { W = Wv; Wt = wtv; }
  __shared__ float t[32][33];
  int tx = threadIdx.x, ty = threadIdx.y;
  int k0 = blockIdx.y * 32, c0 = blockIdx.x * 32;
#pragma unroll
  for (int i = 0; i < 4; ++i)
    t[ty + 8*i][tx] = W[(size_t)(k0 + ty + 8*i) * DOUT + c0 + tx];
  __syncthreads();
#pragma unroll
  for (int i = 0; i < 4; ++i)
    Wt[(size_t)(c0 + ty + 8*i) * DIN + k0 + tx] = __float2bfloat16(t[tx][ty + 8*i]);
}

// ---- QKV GEMM, BK=64, double-buffered, swizzled LDS, counted-vmcnt pipeline,
// XCD-chunked tile swizzle. q (z=0, pre-scaled by QSCALE), k (z=1): [b][h][s][d];
// v (z=2): [b][h][d][s]. ----
__global__ __launch_bounds__(256) void k_qkv(
    const __hip_bfloat16* __restrict__ xb,
    const __hip_bfloat16* __restrict__ wq, const __hip_bfloat16* __restrict__ wk,
    const __hip_bfloat16* __restrict__ wv,
    __hip_bfloat16* __restrict__ qb, __hip_bfloat16* __restrict__ kb,
    __hip_bfloat16* __restrict__ vb) {
  __shared__ __hip_bfloat16 smem[32768];  // A0|A1|B0|B1, 8192 elems each (64KB)

  const __hip_bfloat16* wt; __hip_bfloat16* outp;
  if (blockIdx.z == 0)      { wt = wq; outp = qb; }
  else if (blockIdx.z == 1) { wt = wk; outp = kb; }
  else                      { wt = wv; outp = vb; }

  // XCD-chunked swizzle (T1): XCD = lin%8 owns 32 contiguous tiles = 4 row-
  // panels x all 8 col-tiles -> per-XCD L2 set = 1MB A + 2MB B < 4MB.
  const int lin = blockIdx.y * 8 + blockIdx.x;   // 0..255
  const int nl = (lin & 7) * 32 + (lin >> 3);
  const int row0 = (nl >> 3) * 128, col0 = (nl & 7) * 128;

  const int tid = threadIdx.x, w = tid >> 6, l = tid & 63;
  const int mw = (w >> 1) * 64, nw = (w & 1) * 64;

  const floatx4 fz = {0.f, 0.f, 0.f, 0.f};
  floatx4 acc[4][4];
#pragma unroll
  for (int m = 0; m < 4; ++m)
#pragma unroll
    for (int n = 0; n < 4; ++n) acc[m][n] = fz;

#pragma unroll
  for (int i = 0; i < 4; ++i) {
    stage64(xb + (size_t)row0 * DIN, DIN, smem, w*4+i, l);
    stage64(wt + (size_t)col0 * DIN, DIN, smem + 16384, w*4+i, l);
  }

  for (int kt = 0; kt < 16; ++kt) {
    int cur = kt & 1;
    __hip_bfloat16* Ac = smem + cur * 8192;
    __hip_bfloat16* Bc = smem + 16384 + cur * 8192;
    if (kt < 15) {
      int kk = (kt + 1) * 64;
      __hip_bfloat16* An = smem + (cur ^ 1) * 8192;
      __hip_bfloat16* Bn = smem + 16384 + (cur ^ 1) * 8192;
#pragma unroll
      for (int i = 0; i < 4; ++i) {
        stage64(xb + (size_t)row0 * DIN + kk, DIN, An, w*4+i, l);
        stage64(wt + (size_t)col0 * DIN + kk, DIN, Bn, w*4+i, l);
      }
      WAITV8();   // own loads for tile kt done; kt+1's 8 stay in flight
    } else {
      WAITV0();
    }
    SBAR();       // all waves' loads for tile kt landed
    short8 a[4][2], b[4][2];
#pragma unroll
    for (int m = 0; m < 4; ++m)
#pragma unroll
      for (int ks = 0; ks < 2; ++ks)
        a[m][ks] = frag64(Ac, mw + m*16 + (l & 15), ks, l);
#pragma unroll
    for (int n = 0; n < 4; ++n)
#pragma unroll
      for (int ks = 0; ks < 2; ++ks)
        b[n][ks] = frag64(Bc, nw + n*16 + (l & 15), ks, l);
#pragma unroll
    for (int ks = 0; ks < 2; ++ks)
#pragma unroll
      for (int m = 0; m < 4; ++m)
#pragma unroll
        for (int n = 0; n < 4; ++n)
          acc[m][n] = MFMA16(a[m][ks], b[n][ks], acc[m][n]);
    SBAR();       // reads of buf[cur] done before next iter's issue overwrites it
  }

  int bb2 = row0 >> 11, sbase = row0 & (SS - 1);
  if (blockIdx.z == 2) {
    // V: transpose through LDS (padded stride 136), then 16B coalesced stores.
    __hip_bfloat16* Vt2 = smem;
#pragma unroll
    for (int m = 0; m < 4; ++m)
#pragma unroll
      for (int n = 0; n < 4; ++n)
#pragma unroll
        for (int r4 = 0; r4 < 4; ++r4) {
          int r = mw + m*16 + ((l >> 4) << 2) + r4;
          int c = nw + n*16 + (l & 15);
          Vt2[c * 136 + r] = __float2bfloat16(acc[m][n][r4]);
        }
    __syncthreads();
#pragma unroll
    for (int i = 0; i < 8; ++i) {
      int drow = (tid >> 4) + i * 16;
      int scol = (tid & 15) * 8;
      int colg = col0 + drow, hh = colg >> 6, d = colg & 63;
      *(short8*)(outp + (((size_t)bb2 * NH + hh) * HD + d) * SS + sbase + scol) =
          *(const short8*)&Vt2[drow * 136 + scol];
    }
  } else {
    // Q/K: repack through LDS row-major [128][136], then 16B coalesced stores.
    float sc = (blockIdx.z == 0) ? QSCALE : 1.0f;
    __hip_bfloat16* T2 = smem;
#pragma unroll
    for (int m = 0; m < 4; ++m)
#pragma unroll
      for (int n = 0; n < 4; ++n)
#pragma unroll
        for (int r4 = 0; r4 < 4; ++r4) {
          int r = mw + m*16 + ((l >> 4) << 2) + r4;   // s-index in tile
          int c = nw + n*16 + (l & 15);               // d/head-col in tile
          T2[r * 136 + c] = __float2bfloat16(acc[m][n][r4] * sc);
        }
    __syncthreads();
#pragma unroll
    for (int i = 0; i < 8; ++i) {
      int r = (tid >> 4) + i * 16;          // 0..127 row (s)
      int c = (tid & 15) * 8;               // 0..120 col (d)
      int colg = col0 + c, hh = colg >> 6, d = colg & 63;
      *(short8*)(outp + (((size_t)bb2 * NH + hh) * SS + sbase + r) * HD + d) =
          *(const short8*)&T2[r * 136 + c];
    }
  }
}

// ---- pass A: Z[k] = sum_{q>=k} exp2(S'), then scale V columns by 1/Z in place.
// One j (64 k-columns) per block; grid (32 bh, 32 j), 3 blocks/CU co-resident. ----
__global__ __launch_bounds__(256) void k_cstat(const __hip_bfloat16* __restrict__ qb,
                                               const __hip_bfloat16* __restrict__ kb,
                                               __hip_bfloat16* __restrict__ vtb) {
  __shared__ __hip_bfloat16 smem[20480];  // Kt 4096 | Qt0 8192 | Qt1 8192 (40KB)
  __shared__ float red[4][64];
  __shared__ float zl[64];
  __hip_bfloat16* Kt = smem;
  const int bh = blockIdx.x;
  const int j = blockIdx.y;
  const int tid = threadIdx.x, w = tid >> 6, l = tid & 63;
  const int k0 = j * 64;
  const int t0 = j >> 1, niter = 16 - t0;

#pragma unroll
  for (int i = 0; i < 2; ++i)
    stage64(kb + ((size_t)bh * SS + k0) * HD, HD, Kt, w*2+i, l);
#pragma unroll
  for (int i = 0; i < 4; ++i)
    stage64(qb + ((size_t)bh * SS + (t0 << 7)) * HD, HD, smem + 4096, w*4+i, l);

  short8 kf[4][2];
  float csum[4] = {0.f, 0.f, 0.f, 0.f};
  for (int it = 0; it < niter; ++it) {
    int cur = it & 1;
    __hip_bfloat16* Qc = smem + 4096 + cur * 8192;
    int q0 = (t0 + it) << 7;
    if (it + 1 < niter) {
      __hip_bfloat16* Qn = smem + 4096 + (cur ^ 1) * 8192;
#pragma unroll
      for (int i = 0; i < 4; ++i)
        stage64(qb + ((size_t)bh * SS + q0 + 128) * HD, HD, Qn, w*4+i, l);
      WAITV4();   // K + Q(it) done; Q(it+1)'s 4 in flight
    } else {
      WAITV0();
    }
    SBAR();
    if (it == 0) {
#pragma unroll
      for (int n = 0; n < 4; ++n)
#pragma unroll
        for (int ks = 0; ks < 2; ++ks)
          kf[n][ks] = frag64(Kt, n*16 + (l & 15), ks, l);
    }
    int qw = q0 + w * 32;
    if (qw + 31 >= k0) {
      short8 qa[2][2];
#pragma unroll
      for (int mm = 0; mm < 2; ++mm)
#pragma unroll
        for (int ks = 0; ks < 2; ++ks)
          qa[mm][ks] = frag64(Qc, w*32 + mm*16 + (l & 15), ks, l);
      floatx4 s[2][4];
#pragma unroll
      for (int mm = 0; mm < 2; ++mm)
#pragma unroll
        for (int n = 0; n < 4; ++n) {
          floatx4 t = {0.f, 0.f, 0.f, 0.f};
#pragma unroll
          for (int ks = 0; ks < 2; ++ks) t = MFMA16(qa[mm][ks], kf[n][ks], t);
          s[mm][n] = t;
        }
      bool dia = (k0 + 63 > qw);
#pragma unroll
      for (int mm = 0; mm < 2; ++mm)
#pragma unroll
        for (int n = 0; n < 4; ++n)
#pragma unroll
          for (int r4 = 0; r4 < 4; ++r4) {
            float e = EXP2F(s[mm][n][r4]);
            if (dia) {
              int q = qw + mm*16 + ((l >> 4) << 2) + r4;
              int k = k0 + n*16 + (l & 15);
              if (k > q) e = 0.f;
            }
            csum[n] += e;
          }
    }
    SBAR();
  }

#pragma unroll
  for (int n = 0; n < 4; ++n) {
    csum[n] += __shfl_xor(csum[n], 16);
    csum[n] += __shfl_xor(csum[n], 32);
    if (l < 16) red[w][n*16 + l] = csum[n];
  }
  __syncthreads();
  if (tid < 64)
    zl[tid] = 1.0f / (red[0][tid] + red[1][tid] + red[2][tid] + red[3][tid]);
  __syncthreads();
  // scale vtb columns [k0, k0+64) by 1/Z (in place; disjoint per block)
#pragma unroll
  for (int i = 0; i < 4; ++i) {
    int d = (tid >> 4) + i * 16;
    int c = (tid & 15) * 4;
    size_t base = ((size_t)bh * HD + d) * SS + k0 + c;
    short4 v = *(const short4*)(vtb + base);
    __hip_bfloat16* hp = (__hip_bfloat16*)&v;
#pragma unroll
    for (int jv = 0; jv < 4; ++jv)
      hp[jv] = __float2bfloat16(__bfloat162float(hp[jv]) * zl[c + jv]);
    *(short4*)(vtb + base) = v;
  }
}

// ---- pass B: ctx[q,:] = sum_{k<=q} exp2(S') * Vs[k,:]  (Vs has 1/Z folded).
// K-SPLIT x2: 512 blocks x 8 waves (512 thr), 64KB LDS -> 2 independent
// blocks/CU = 4 waves/SIMD from 2 unaligned barrier groups (r13 win).
// EQUAL-LENGTH pairing: blocks i and i+256 (co-located at exactly 2/CU) share
// the same tb (different bh: 0-15 vs 16-31) so both stay resident the full
// duration; tb-major descending dispatch. Wave w: row-group g = w&3 (rows
// Q0+g+4c), k-half s = w>>2 (tiles s, s+2, ...). Private K/V dbuf per half:
// smem + s*16384 [K0|K1|V0|V1 x 4096]. Single acc[2], 4-deep QK chain.
__global__ __launch_bounds__(512, 4) void k_ctx(const __hip_bfloat16* __restrict__ qb,
                                                const __hip_bfloat16* __restrict__ kb,
                                                const __hip_bfloat16* __restrict__ vtb,
                                                float* __restrict__ outp) {
  __shared__ __hip_bfloat16 smem[32768];  // 64KB
  const int i = blockIdx.x;
  const int j = i & 255;
  const int tb = 15 - (j >> 4);                 // same tb for i and i+256
  const int bh = (j & 15) + ((i >> 8) << 4);    // bh 0-15 first round, 16-31 second
  const int bb = bh >> 4, h = bh & 15;
  const int Q0 = tb * 128;
  const int tid = threadIdx.x, w = tid >> 6, l = tid & 63;
  const int g = w & 3, s = w >> 2;
  const int hi = l >> 5;
  const int qg = Q0 + g + 4 * (l & 31);   // lane's q-row (ST column c = l&31)
  const int nkt = 2 * (tb + 1);           // 64-wide k-tiles in causal range (even)
  const int nit = nkt >> 1;               // iterations per k-half
  __hip_bfloat16* qsm = smem + s * 16384; // half's region: K0|K1|V0|V1

  // Q fragments: lane q-row = qg, elems d = hc*16 + hi*8 .. +7. Drain vmcnt in
  // the prologue so loop's counted waits only see staging ops.
  short8 qf[4];
  {
    const __hip_bfloat16* qrow = qb + ((size_t)bh * SS + qg) * HD + hi * 8;
#pragma unroll
    for (int hc = 0; hc < 4; ++hc)
      qf[hc] = *(const short8*)(qrow + hc * 16);
  }
  asm volatile("" :: "v"(qf[0]), "v"(qf[1]), "v"(qf[2]), "v"(qf[3]));
  WAITV0();

  // stage half's first k-tile (index s): 2 K-chunks + 2 V-chunks per wave
  {
    int kn = s << 6;
#pragma unroll
    for (int ii = 0; ii < 2; ++ii) {
      stage64(kb + ((size_t)bh * SS + kn) * HD, HD, qsm, g*2+ii, l);
      stage64(vtb + (size_t)bh * HD * SS + kn, SS, qsm + 8192, g*2+ii, l);
    }
  }

  const floatx16 fz16 = {0,0,0,0,0,0,0,0,0,0,0,0,0,0,0,0};
  floatx16 acc[2];
  acc[0] = fz16; acc[1] = fz16;

  for (int it = 0; it < nit; ++it) {
    int cur = it & 1;
    __hip_bfloat16* Kc = qsm + cur * 4096;
    __hip_bfloat16* Vc = qsm + 8192 + cur * 4096;
    const int myk = s + 2 * it;
    const int nxt = myk + 2;
    if (nxt < nkt) {
      int kn = nxt << 6;
#pragma unroll
      for (int ii = 0; ii < 2; ++ii) {
        stage64(kb + ((size_t)bh * SS + kn) * HD, HD, qsm + (cur^1) * 4096, g*2+ii, l);
        stage64(vtb + (size_t)bh * HD * SS + kn, SS, qsm + 8192 + (cur^1) * 4096, g*2+ii, l);
      }
      WAITV4();   // tile myk's 4 landed; nxt's 4 stay in flight
    } else {
      WAITV0();
    }
    SBAR();       // buf[cur] fully populated

    {
      const int k0 = myk << 6;
      // ST halves: ST[k0+32H+roff][c], roff = (r&3)+8*(r>>2)+4*hi
      floatx16 st[2];
#pragma unroll
      for (int H = 0; H < 2; ++H) {
        floatx16 t = fz16;
#pragma unroll
        for (int hc = 0; hc < 4; ++hc)
          t = MFMA32(frag32(Kc, H*32 + (l & 31), hc, l), qf[hc], t);
        st[H] = t;
      }
      // exp2 + causal mask + pack to bf16 pairs: pk[H][m][pr] holds
      // k = k0 + 32H + 8m + 4hi + 2pr + {0,1}
      const bool dia = (k0 + 63 > Q0 + g);   // min q in wave = Q0 + g
      unsigned pk[2][4][2];
#pragma unroll
      for (int H = 0; H < 2; ++H)
#pragma unroll
        for (int m = 0; m < 4; ++m)
#pragma unroll
          for (int pr = 0; pr < 2; ++pr) {
            float e0 = EXP2F(st[H][m*4 + pr*2]);
            float e1 = EXP2F(st[H][m*4 + pr*2 + 1]);
            if (dia) {
              int kb0 = k0 + H*32 + m*8 + hi*4 + pr*2;
              if (kb0 > qg)     e0 = 0.f;
              if (kb0 + 1 > qg) e1 = 0.f;
            }
            pk[H][m][pr] = (unsigned)__bfloat16_as_ushort(__float2bfloat16(e0)) |
                           ((unsigned)__bfloat16_as_ushort(__float2bfloat16(e1)) << 16);
          }
      // PV: 4 k-chunks of 16; A-frag k = 16ks + hi*8 + 0..7.
#pragma unroll
      for (int ks = 0; ks < 4; ++ks) {
        const int H = ks >> 1, mb = (ks & 1) * 2;
        unsigned keep0 = hi ? pk[H][mb+1][0] : pk[H][mb][0];
        unsigned keep1 = hi ? pk[H][mb+1][1] : pk[H][mb][1];
        unsigned send0 = hi ? pk[H][mb][0]   : pk[H][mb+1][0];
        unsigned send1 = hi ? pk[H][mb][1]   : pk[H][mb+1][1];
        unsigned recv0 = (unsigned)__shfl_xor((int)send0, 32);
        unsigned recv1 = (unsigned)__shfl_xor((int)send1, 32);
        union { unsigned u[4]; short8 sv; } pa;
        pa.u[0] = hi ? recv0 : keep0;
        pa.u[1] = hi ? recv1 : keep1;
        pa.u[2] = hi ? keep0 : recv0;
        pa.u[3] = hi ? keep1 : recv1;
#pragma unroll
        for (int dn = 0; dn < 2; ++dn)
          acc[dn] = MFMA32(pa.sv, frag32(Vc, dn*32 + (l & 31), ks, l), acc[dn]);
      }
    }
    SBAR();       // reads of buf[cur] done before next iter overwrites it
  }

  // ---- reduce partials across the two k-halves ----
  float* fsm = (float*)smem;   // staging dead after final SBAR; 8192 floats used
  if (s == 1) {
    float* dst = fsm + g * 2048;
#pragma unroll
    for (int dn = 0; dn < 2; ++dn)
#pragma unroll
      for (int r = 0; r < 16; ++r)
        dst[(dn * 16 + r) * 64 + l] = acc[dn][r];
  }
  __syncthreads();
  if (s == 0) {
    const float* src = fsm + g * 2048;
#pragma unroll
    for (int dn = 0; dn < 2; ++dn)
#pragma unroll
      for (int r = 0; r < 16; ++r)
        acc[dn][r] += src[(dn * 16 + r) * 64 + l];
#pragma unroll
    for (int dn = 0; dn < 2; ++dn)
#pragma unroll
      for (int r = 0; r < 16; ++r) {
        int q = Q0 + g + 4 * ((r & 3) + 8*(r >> 2) + 4*hi);
        outp[((size_t)bb * SS + q) * DOUT + h * HD + dn*32 + (l & 31)] = acc[dn][r];
      }
  }
}

extern "C" void kernel_launch(void* const* d_in, const int* in_sizes, int n_in,
                              void* d_out, int out_size, void* d_ws, size_t ws_size,
                              hipStream_t stream) {
  const float* x  = (const float*)d_in[0];
  const float* Wq = (const float*)d_in[1];
  const float* Wk = (const float*)d_in[2];
  const float* Wv = (const float*)d_in[3];
  float* out = (float*)d_out;
  char* ws = (char*)d_ws;

  __hip_bfloat16* xb  = (__hip_bfloat16*)(ws);                   // 8 MB
  __hip_bfloat16* wtq = (__hip_bfloat16*)(ws + (8ull  << 20));   // 2 MB
  __hip_bfloat16* wtk = (__hip_bfloat16*)(ws + (10ull << 20));   // 2 MB
  __hip_bfloat16* wtv = (__hip_bfloat16*)(ws + (12ull << 20));   // 2 MB
  __hip_bfloat16* qb  = (__hip_bfloat16*)(ws + (14ull << 20));   // 8 MB [b][h][s][d], pre-scaled
  __hip_bfloat16* kb  = (__hip_bfloat16*)(ws + (22ull << 20));   // 8 MB [b][h][s][d]
  __hip_bfloat16* vtb = (__hip_bfloat16*)(ws + (30ull << 20));   // 8 MB [b][h][d][s], 1/Z folded

  k_cvt_x<<<4096, 256, 0, stream>>>(x, xb);
  dim3 tb(32, 8);
  k_twb<<<dim3(32, 32, 3), tb, 0, stream>>>(Wq, Wk, Wv, wtq, wtk, wtv);
  k_qkv<<<dim3(8, 32, 3), 256, 0, stream>>>(xb, wtq, wtk, wtv, qb, kb, vtb);
  k_cstat<<<dim3(32, 32), 256, 0, stream>>>(qb, kb, vtb);
  k_ctx<<<dim3(512), 512, 0, stream>>>(qb, kb, vtb, out);
}

// Round 17
// 100.480 us; speedup vs baseline: 1.1523x; 1.1523x over previous
//
#include <hip/hip_runtime.h>
#include <hip/hip_bf16.h>

// CausalSelfAttention quirk kernel: softmax over QUERY axis, scale sqrt(D_OUT)=32.
// w[q,k] = exp(S/32)/Z[k], Z[k] = sum_{q>=k} exp(S/32)  (per-COLUMN denominator).
// Pass A (k_cstat) computes Z and folds 1/Z into V; pass B (k_ctx) recomputes S
// tile-wise and does PV. 1/32*log2e folded into Q at the QKV epilogue.
// Round 17: k_ctx mapping reverted to r13/r15 big+small pairing (r16's equal-
// length pairing broke CU load balance: makespan 21 vs 16.3 shared-iters).
// k_cvt_x widened to 8 floats/thread (16B/lane loads). Rest = r15 (best, 100.7).

typedef __attribute__((ext_vector_type(8))) short short8;
typedef __attribute__((ext_vector_type(4))) float floatx4;
typedef __attribute__((ext_vector_type(16))) float floatx16;

#define SS 2048
#define DIN 1024
#define DOUT 1024
#define NH 16
#define HD 64
#define QSCALE 0.04508422002778011f  // (1/32) * log2(e)

#define MFMA16(a,b,c) __builtin_amdgcn_mfma_f32_16x16x32_bf16((a),(b),(c),0,0,0)
#define MFMA32(a,b,c) __builtin_amdgcn_mfma_f32_32x32x16_bf16((a),(b),(c),0,0,0)
#define EXP2F(x) __builtin_amdgcn_exp2f(x)
#define SBAR() __builtin_amdgcn_s_barrier()
#define WAITV0() asm volatile("s_waitcnt vmcnt(0)" ::: "memory")
#define WAITV4() asm volatile("s_waitcnt vmcnt(4)" ::: "memory")
#define WAITV8() asm volatile("s_waitcnt vmcnt(8)" ::: "memory")

__device__ __forceinline__ void gl_lds16(const void* g, void* l) {
  __builtin_amdgcn_global_load_lds((const __attribute__((address_space(1))) void*)g,
                                   (__attribute__((address_space(3))) void*)l, 16, 0, 0);
}

// Stage an 8-row chunk `c` of a [*][64] bf16 tile (global row stride `stride` elems)
// into LDS at lds + c*512, linear dest. XOR-swizzle applied on the GLOBAL source
// slot so that LDS[r][slot s] holds global slot s^(r&7).
__device__ __forceinline__ void stage64(const __hip_bfloat16* __restrict__ src, int stride,
                                        __hip_bfloat16* lds, int c, int l) {
  int r = c * 8 + (l >> 3);
  int cc = ((l & 7) ^ ((l >> 3) & 7)) * 8;
  gl_lds16(src + (size_t)r * stride + cc, lds + c * 512);
}

// 16x16x32 fragment from a [*][64] swizzled tile: row `row`, k-slot ks*4+(l>>4).
__device__ __forceinline__ short8 frag64(const __hip_bfloat16* lds, int row, int ks, int l) {
  return *(const short8*)&lds[row * 64 + (((ks * 4 + (l >> 4)) ^ (row & 7)) * 8)];
}

// 32x32x16 fragment: row `row` (0..63), 16-wide k-chunk `subk` (0..3), elems
// k = subk*16 + (l>>5)*8 + 0..7.
__device__ __forceinline__ short8 frag32(const __hip_bfloat16* lds, int row, int subk, int l) {
  return *(const short8*)&lds[row * 64 + (((subk * 2 + (l >> 5)) ^ (row & 7)) * 8)];
}

// ---- convert x fp32 -> bf16, 8 elems/thread ----
__global__ __launch_bounds__(256) void k_cvt_x(const float* __restrict__ x,
                                               __hip_bfloat16* __restrict__ xb) {
  size_t i = ((size_t)blockIdx.x * 256 + threadIdx.x) * 8;
  float4 v0 = *(const float4*)(x + i);
  float4 v1 = *(const float4*)(x + i + 4);
  union { __hip_bfloat16 h[8]; short8 s; } u;
  u.h[0] = __float2bfloat16(v0.x); u.h[1] = __float2bfloat16(v0.y);
  u.h[2] = __float2bfloat16(v0.z); u.h[3] = __float2bfloat16(v0.w);
  u.h[4] = __float2bfloat16(v1.x); u.h[5] = __float2bfloat16(v1.y);
  u.h[6] = __float2bfloat16(v1.z); u.h[7] = __float2bfloat16(v1.w);
  *(short8*)(xb + i) = u.s;
}

// ---- transpose + convert W [k][c] fp32 -> Wt [c][k] bf16; z selects Q/K/V ----
__global__ void k_twb(const float* __restrict__ Wq, const float* __restrict__ Wk,
                      const float* __restrict__ Wv,
                      __hip_bfloat16* __restrict__ wtq, __hip_bfloat16* __restrict__ wtk,
                      __hip_bfloat16* __restrict__ wtv) {
  const float* W; __hip_bfloat16* Wt;
  if (blockIdx.z == 0)      { W = Wq; Wt = wtq; }
  else if (blockIdx.z == 1) { W = Wk; Wt = wtk; }
  else                      { W = Wv; Wt = wtv; }
  __shared__ float t[32][33];
  int tx = threadIdx.x, ty = threadIdx.y;
  int k0 = blockIdx.y * 32, c0 = blockIdx.x * 32;
#pragma unroll
  for (int i = 0; i < 4; ++i)
    t[ty + 8*i][tx] = W[(size_t)(k0 + ty + 8*i) * DOUT + c0 + tx];
  __syncthreads();
#pragma unroll
  for (int i = 0; i < 4; ++i)
    Wt[(size_t)(c0 + ty + 8*i) * DIN + k0 + tx] = __float2bfloat16(t[tx][ty + 8*i]);
}

// ---- QKV GEMM, BK=64, double-buffered, swizzled LDS, counted-vmcnt pipeline,
// XCD-chunked tile swizzle. q (z=0, pre-scaled by QSCALE), k (z=1): [b][h][s][d];
// v (z=2): [b][h][d][s]. ----
__global__ __launch_bounds__(256) void k_qkv(
    const __hip_bfloat16* __restrict__ xb,
    const __hip_bfloat16* __restrict__ wq, const __hip_bfloat16* __restrict__ wk,
    const __hip_bfloat16* __restrict__ wv,
    __hip_bfloat16* __restrict__ qb, __hip_bfloat16* __restrict__ kb,
    __hip_bfloat16* __restrict__ vb) {
  __shared__ __hip_bfloat16 smem[32768];  // A0|A1|B0|B1, 8192 elems each (64KB)

  const __hip_bfloat16* wt; __hip_bfloat16* outp;
  if (blockIdx.z == 0)      { wt = wq; outp = qb; }
  else if (blockIdx.z == 1) { wt = wk; outp = kb; }
  else                      { wt = wv; outp = vb; }

  // XCD-chunked swizzle (T1): XCD = lin%8 owns 32 contiguous tiles = 4 row-
  // panels x all 8 col-tiles -> per-XCD L2 set = 1MB A + 2MB B < 4MB.
  const int lin = blockIdx.y * 8 + blockIdx.x;   // 0..255
  const int nl = (lin & 7) * 32 + (lin >> 3);
  const int row0 = (nl >> 3) * 128, col0 = (nl & 7) * 128;

  const int tid = threadIdx.x, w = tid >> 6, l = tid & 63;
  const int mw = (w >> 1) * 64, nw = (w & 1) * 64;

  const floatx4 fz = {0.f, 0.f, 0.f, 0.f};
  floatx4 acc[4][4];
#pragma unroll
  for (int m = 0; m < 4; ++m)
#pragma unroll
    for (int n = 0; n < 4; ++n) acc[m][n] = fz;

#pragma unroll
  for (int i = 0; i < 4; ++i) {
    stage64(xb + (size_t)row0 * DIN, DIN, smem, w*4+i, l);
    stage64(wt + (size_t)col0 * DIN, DIN, smem + 16384, w*4+i, l);
  }

  for (int kt = 0; kt < 16; ++kt) {
    int cur = kt & 1;
    __hip_bfloat16* Ac = smem + cur * 8192;
    __hip_bfloat16* Bc = smem + 16384 + cur * 8192;
    if (kt < 15) {
      int kk = (kt + 1) * 64;
      __hip_bfloat16* An = smem + (cur ^ 1) * 8192;
      __hip_bfloat16* Bn = smem + 16384 + (cur ^ 1) * 8192;
#pragma unroll
      for (int i = 0; i < 4; ++i) {
        stage64(xb + (size_t)row0 * DIN + kk, DIN, An, w*4+i, l);
        stage64(wt + (size_t)col0 * DIN + kk, DIN, Bn, w*4+i, l);
      }
      WAITV8();   // own loads for tile kt done; kt+1's 8 stay in flight
    } else {
      WAITV0();
    }
    SBAR();       // all waves' loads for tile kt landed
    short8 a[4][2], b[4][2];
#pragma unroll
    for (int m = 0; m < 4; ++m)
#pragma unroll
      for (int ks = 0; ks < 2; ++ks)
        a[m][ks] = frag64(Ac, mw + m*16 + (l & 15), ks, l);
#pragma unroll
    for (int n = 0; n < 4; ++n)
#pragma unroll
      for (int ks = 0; ks < 2; ++ks)
        b[n][ks] = frag64(Bc, nw + n*16 + (l & 15), ks, l);
#pragma unroll
    for (int ks = 0; ks < 2; ++ks)
#pragma unroll
      for (int m = 0; m < 4; ++m)
#pragma unroll
        for (int n = 0; n < 4; ++n)
          acc[m][n] = MFMA16(a[m][ks], b[n][ks], acc[m][n]);
    SBAR();       // reads of buf[cur] done before next iter's issue overwrites it
  }

  int bb2 = row0 >> 11, sbase = row0 & (SS - 1);
  if (blockIdx.z == 2) {
    // V: transpose through LDS (padded stride 136), then 16B coalesced stores.
    __hip_bfloat16* Vt2 = smem;
#pragma unroll
    for (int m = 0; m < 4; ++m)
#pragma unroll
      for (int n = 0; n < 4; ++n)
#pragma unroll
        for (int r4 = 0; r4 < 4; ++r4) {
          int r = mw + m*16 + ((l >> 4) << 2) + r4;
          int c = nw + n*16 + (l & 15);
          Vt2[c * 136 + r] = __float2bfloat16(acc[m][n][r4]);
        }
    __syncthreads();
#pragma unroll
    for (int i = 0; i < 8; ++i) {
      int drow = (tid >> 4) + i * 16;
      int scol = (tid & 15) * 8;
      int colg = col0 + drow, hh = colg >> 6, d = colg & 63;
      *(short8*)(outp + (((size_t)bb2 * NH + hh) * HD + d) * SS + sbase + scol) =
          *(const short8*)&Vt2[drow * 136 + scol];
    }
  } else {
    // Q/K: repack through LDS row-major [128][136], then 16B coalesced stores.
    float sc = (blockIdx.z == 0) ? QSCALE : 1.0f;
    __hip_bfloat16* T2 = smem;
#pragma unroll
    for (int m = 0; m < 4; ++m)
#pragma unroll
      for (int n = 0; n < 4; ++n)
#pragma unroll
        for (int r4 = 0; r4 < 4; ++r4) {
          int r = mw + m*16 + ((l >> 4) << 2) + r4;   // s-index in tile
          int c = nw + n*16 + (l & 15);               // d/head-col in tile
          T2[r * 136 + c] = __float2bfloat16(acc[m][n][r4] * sc);
        }
    __syncthreads();
#pragma unroll
    for (int i = 0; i < 8; ++i) {
      int r = (tid >> 4) + i * 16;          // 0..127 row (s)
      int c = (tid & 15) * 8;               // 0..120 col (d)
      int colg = col0 + c, hh = colg >> 6, d = colg & 63;
      *(short8*)(outp + (((size_t)bb2 * NH + hh) * SS + sbase + r) * HD + d) =
          *(const short8*)&T2[r * 136 + c];
    }
  }
}

// ---- pass A: Z[k] = sum_{q>=k} exp2(S'), then scale V columns by 1/Z in place.
// One j (64 k-columns) per block; grid (32 bh, 32 j), 3 blocks/CU co-resident. ----
__global__ __launch_bounds__(256) void k_cstat(const __hip_bfloat16* __restrict__ qb,
                                               const __hip_bfloat16* __restrict__ kb,
                                               __hip_bfloat16* __restrict__ vtb) {
  __shared__ __hip_bfloat16 smem[20480];  // Kt 4096 | Qt0 8192 | Qt1 8192 (40KB)
  __shared__ float red[4][64];
  __shared__ float zl[64];
  __hip_bfloat16* Kt = smem;
  const int bh = blockIdx.x;
  const int j = blockIdx.y;
  const int tid = threadIdx.x, w = tid >> 6, l = tid & 63;
  const int k0 = j * 64;
  const int t0 = j >> 1, niter = 16 - t0;

#pragma unroll
  for (int i = 0; i < 2; ++i)
    stage64(kb + ((size_t)bh * SS + k0) * HD, HD, Kt, w*2+i, l);
#pragma unroll
  for (int i = 0; i < 4; ++i)
    stage64(qb + ((size_t)bh * SS + (t0 << 7)) * HD, HD, smem + 4096, w*4+i, l);

  short8 kf[4][2];
  float csum[4] = {0.f, 0.f, 0.f, 0.f};
  for (int it = 0; it < niter; ++it) {
    int cur = it & 1;
    __hip_bfloat16* Qc = smem + 4096 + cur * 8192;
    int q0 = (t0 + it) << 7;
    if (it + 1 < niter) {
      __hip_bfloat16* Qn = smem + 4096 + (cur ^ 1) * 8192;
#pragma unroll
      for (int i = 0; i < 4; ++i)
        stage64(qb + ((size_t)bh * SS + q0 + 128) * HD, HD, Qn, w*4+i, l);
      WAITV4();   // K + Q(it) done; Q(it+1)'s 4 in flight
    } else {
      WAITV0();
    }
    SBAR();
    if (it == 0) {
#pragma unroll
      for (int n = 0; n < 4; ++n)
#pragma unroll
        for (int ks = 0; ks < 2; ++ks)
          kf[n][ks] = frag64(Kt, n*16 + (l & 15), ks, l);
    }
    int qw = q0 + w * 32;
    if (qw + 31 >= k0) {
      short8 qa[2][2];
#pragma unroll
      for (int mm = 0; mm < 2; ++mm)
#pragma unroll
        for (int ks = 0; ks < 2; ++ks)
          qa[mm][ks] = frag64(Qc, w*32 + mm*16 + (l & 15), ks, l);
      floatx4 s[2][4];
#pragma unroll
      for (int mm = 0; mm < 2; ++mm)
#pragma unroll
        for (int n = 0; n < 4; ++n) {
          floatx4 t = {0.f, 0.f, 0.f, 0.f};
#pragma unroll
          for (int ks = 0; ks < 2; ++ks) t = MFMA16(qa[mm][ks], kf[n][ks], t);
          s[mm][n] = t;
        }
      bool dia = (k0 + 63 > qw);
#pragma unroll
      for (int mm = 0; mm < 2; ++mm)
#pragma unroll
        for (int n = 0; n < 4; ++n)
#pragma unroll
          for (int r4 = 0; r4 < 4; ++r4) {
            float e = EXP2F(s[mm][n][r4]);
            if (dia) {
              int q = qw + mm*16 + ((l >> 4) << 2) + r4;
              int k = k0 + n*16 + (l & 15);
              if (k > q) e = 0.f;
            }
            csum[n] += e;
          }
    }
    SBAR();
  }

#pragma unroll
  for (int n = 0; n < 4; ++n) {
    csum[n] += __shfl_xor(csum[n], 16);
    csum[n] += __shfl_xor(csum[n], 32);
    if (l < 16) red[w][n*16 + l] = csum[n];
  }
  __syncthreads();
  if (tid < 64)
    zl[tid] = 1.0f / (red[0][tid] + red[1][tid] + red[2][tid] + red[3][tid]);
  __syncthreads();
  // scale vtb columns [k0, k0+64) by 1/Z (in place; disjoint per block)
#pragma unroll
  for (int i = 0; i < 4; ++i) {
    int d = (tid >> 4) + i * 16;
    int c = (tid & 15) * 4;
    size_t base = ((size_t)bh * HD + d) * SS + k0 + c;
    short4 v = *(const short4*)(vtb + base);
    __hip_bfloat16* hp = (__hip_bfloat16*)&v;
#pragma unroll
    for (int jv = 0; jv < 4; ++jv)
      hp[jv] = __float2bfloat16(__bfloat162float(hp[jv]) * zl[c + jv]);
    *(short4*)(vtb + base) = v;
  }
}

// ---- pass B: ctx[q,:] = sum_{k<=q} exp2(S') * Vs[k,:]  (Vs has 1/Z folded).
// K-SPLIT x2: 512 blocks x 8 waves (512 thr), 64KB LDS -> 2 independent
// blocks/CU = 4 waves/SIMD from 2 unaligned barrier groups (r13 win).
// Block i: bh = i&31, tb = (i<256) ? 15-(i>>5) : (i-256)>>5 (CU pairs big+small,
// per-CU load balanced: sum = 17 iters). Wave w: row-group g = w&3 (rows
// Q0+g+4c), k-half s = w>>2 (tiles s, s+2, ...). Private K/V dbuf per half:
// smem + s*16384 [K0|K1|V0|V1 x 4096]. Single acc[2], 4-deep QK chain.
__global__ __launch_bounds__(512, 4) void k_ctx(const __hip_bfloat16* __restrict__ qb,
                                                const __hip_bfloat16* __restrict__ kb,
                                                const __hip_bfloat16* __restrict__ vtb,
                                                float* __restrict__ outp) {
  __shared__ __hip_bfloat16 smem[32768];  // 64KB
  const int i = blockIdx.x;
  const int bh = i & 31, bb = bh >> 4, h = bh & 15;
  const int tb = (i < 256) ? (15 - (i >> 5)) : ((i - 256) >> 5);
  const int Q0 = tb * 128;
  const int tid = threadIdx.x, w = tid >> 6, l = tid & 63;
  const int g = w & 3, s = w >> 2;
  const int hi = l >> 5;
  const int qg = Q0 + g + 4 * (l & 31);   // lane's q-row (ST column c = l&31)
  const int nkt = 2 * (tb + 1);           // 64-wide k-tiles in causal range (even)
  const int nit = nkt >> 1;               // iterations per k-half
  __hip_bfloat16* qsm = smem + s * 16384; // half's region: K0|K1|V0|V1

  // Q fragments: lane q-row = qg, elems d = hc*16 + hi*8 .. +7. Drain vmcnt in
  // the prologue so loop's counted waits only see staging ops.
  short8 qf[4];
  {
    const __hip_bfloat16* qrow = qb + ((size_t)bh * SS + qg) * HD + hi * 8;
#pragma unroll
    for (int hc = 0; hc < 4; ++hc)
      qf[hc] = *(const short8*)(qrow + hc * 16);
  }
  asm volatile("" :: "v"(qf[0]), "v"(qf[1]), "v"(qf[2]), "v"(qf[3]));
  WAITV0();

  // stage half's first k-tile (index s): 2 K-chunks + 2 V-chunks per wave
  {
    int kn = s << 6;
#pragma unroll
    for (int ii = 0; ii < 2; ++ii) {
      stage64(kb + ((size_t)bh * SS + kn) * HD, HD, qsm, g*2+ii, l);
      stage64(vtb + (size_t)bh * HD * SS + kn, SS, qsm + 8192, g*2+ii, l);
    }
  }

  const floatx16 fz16 = {0,0,0,0,0,0,0,0,0,0,0,0,0,0,0,0};
  floatx16 acc[2];
  acc[0] = fz16; acc[1] = fz16;

  for (int it = 0; it < nit; ++it) {
    int cur = it & 1;
    __hip_bfloat16* Kc = qsm + cur * 4096;
    __hip_bfloat16* Vc = qsm + 8192 + cur * 4096;
    const int myk = s + 2 * it;
    const int nxt = myk + 2;
    if (nxt < nkt) {
      int kn = nxt << 6;
#pragma unroll
      for (int ii = 0; ii < 2; ++ii) {
        stage64(kb + ((size_t)bh * SS + kn) * HD, HD, qsm + (cur^1) * 4096, g*2+ii, l);
        stage64(vtb + (size_t)bh * HD * SS + kn, SS, qsm + 8192 + (cur^1) * 4096, g*2+ii, l);
      }
      WAITV4();   // tile myk's 4 landed; nxt's 4 stay in flight
    } else {
      WAITV0();
    }
    SBAR();       // buf[cur] fully populated

    {
      const int k0 = myk << 6;
      // ST halves: ST[k0+32H+roff][c], roff = (r&3)+8*(r>>2)+4*hi
      floatx16 st[2];
#pragma unroll
      for (int H = 0; H < 2; ++H) {
        floatx16 t = fz16;
#pragma unroll
        for (int hc = 0; hc < 4; ++hc)
          t = MFMA32(frag32(Kc, H*32 + (l & 31), hc, l), qf[hc], t);
        st[H] = t;
      }
      // exp2 + causal mask + pack to bf16 pairs: pk[H][m][pr] holds
      // k = k0 + 32H + 8m + 4hi + 2pr + {0,1}
      const bool dia = (k0 + 63 > Q0 + g);   // min q in wave = Q0 + g
      unsigned pk[2][4][2];
#pragma unroll
      for (int H = 0; H < 2; ++H)
#pragma unroll
        for (int m = 0; m < 4; ++m)
#pragma unroll
          for (int pr = 0; pr < 2; ++pr) {
            float e0 = EXP2F(st[H][m*4 + pr*2]);
            float e1 = EXP2F(st[H][m*4 + pr*2 + 1]);
            if (dia) {
              int kb0 = k0 + H*32 + m*8 + hi*4 + pr*2;
              if (kb0 > qg)     e0 = 0.f;
              if (kb0 + 1 > qg) e1 = 0.f;
            }
            pk[H][m][pr] = (unsigned)__bfloat16_as_ushort(__float2bfloat16(e0)) |
                           ((unsigned)__bfloat16_as_ushort(__float2bfloat16(e1)) << 16);
          }
      // PV: 4 k-chunks of 16; A-frag k = 16ks + hi*8 + 0..7.
#pragma unroll
      for (int ks = 0; ks < 4; ++ks) {
        const int H = ks >> 1, mb = (ks & 1) * 2;
        unsigned keep0 = hi ? pk[H][mb+1][0] : pk[H][mb][0];
        unsigned keep1 = hi ? pk[H][mb+1][1] : pk[H][mb][1];
        unsigned send0 = hi ? pk[H][mb][0]   : pk[H][mb+1][0];
        unsigned send1 = hi ? pk[H][mb][1]   : pk[H][mb+1][1];
        unsigned recv0 = (unsigned)__shfl_xor((int)send0, 32);
        unsigned recv1 = (unsigned)__shfl_xor((int)send1, 32);
        union { unsigned u[4]; short8 sv; } pa;
        pa.u[0] = hi ? recv0 : keep0;
        pa.u[1] = hi ? recv1 : keep1;
        pa.u[2] = hi ? keep0 : recv0;
        pa.u[3] = hi ? keep1 : recv1;
#pragma unroll
        for (int dn = 0; dn < 2; ++dn)
          acc[dn] = MFMA32(pa.sv, frag32(Vc, dn*32 + (l & 31), ks, l), acc[dn]);
      }
    }
    SBAR();       // reads of buf[cur] done before next iter overwrites it
  }

  // ---- reduce partials across the two k-halves ----
  float* fsm = (float*)smem;   // staging dead after final SBAR; 8192 floats used
  if (s == 1) {
    float* dst = fsm + g * 2048;
#pragma unroll
    for (int dn = 0; dn < 2; ++dn)
#pragma unroll
      for (int r = 0; r < 16; ++r)
        dst[(dn * 16 + r) * 64 + l] = acc[dn][r];
  }
  __syncthreads();
  if (s == 0) {
    const float* src = fsm + g * 2048;
#pragma unroll
    for (int dn = 0; dn < 2; ++dn)
#pragma unroll
      for (int r = 0; r < 16; ++r)
        acc[dn][r] += src[(dn * 16 + r) * 64 + l];
#pragma unroll
    for (int dn = 0; dn < 2; ++dn)
#pragma unroll
      for (int r = 0; r < 16; ++r) {
        int q = Q0 + g + 4 * ((r & 3) + 8*(r >> 2) + 4*hi);
        outp[((size_t)bb * SS + q) * DOUT + h * HD + dn*32 + (l & 31)] = acc[dn][r];
      }
  }
}

extern "C" void kernel_launch(void* const* d_in, const int* in_sizes, int n_in,
                              void* d_out, int out_size, void* d_ws, size_t ws_size,
                              hipStream_t stream) {
  const float* x  = (const float*)d_in[0];
  const float* Wq = (const float*)d_in[1];
  const float* Wk = (const float*)d_in[2];
  const float* Wv = (const float*)d_in[3];
  float* out = (float*)d_out;
  char* ws = (char*)d_ws;

  __hip_bfloat16* xb  = (__hip_bfloat16*)(ws);                   // 8 MB
  __hip_bfloat16* wtq = (__hip_bfloat16*)(ws + (8ull  << 20));   // 2 MB
  __hip_bfloat16* wtk = (__hip_bfloat16*)(ws + (10ull << 20));   // 2 MB
  __hip_bfloat16* wtv = (__hip_bfloat16*)(ws + (12ull << 20));   // 2 MB
  __hip_bfloat16* qb  = (__hip_bfloat16*)(ws + (14ull << 20));   // 8 MB [b][h][s][d], pre-scaled
  __hip_bfloat16* kb  = (__hip_bfloat16*)(ws + (22ull << 20));   // 8 MB [b][h][s][d]
  __hip_bfloat16* vtb = (__hip_bfloat16*)(ws + (30ull << 20));   // 8 MB [b][h][d][s], 1/Z folded

  k_cvt_x<<<2048, 256, 0, stream>>>(x, xb);
  dim3 tb(32, 8);
  k_twb<<<dim3(32, 32, 3), tb, 0, stream>>>(Wq, Wk, Wv, wtq, wtk, wtv);
  k_qkv<<<dim3(8, 32, 3), 256, 0, stream>>>(xb, wtq, wtk, wtv, qb, kb, vtb);
  k_cstat<<<dim3(32, 32), 256, 0, stream>>>(qb, kb, vtb);
  k_ctx<<<dim3(512), 512, 0, stream>>>(qb, kb, vtb, out);
}

// Round 18
// 97.950 us; speedup vs baseline: 1.1821x; 1.0258x over previous
//
#include <hip/hip_runtime.h>
#include <hip/hip_bf16.h>

// CausalSelfAttention quirk kernel: softmax over QUERY axis, scale sqrt(D_OUT)=32.
// w[q,k] = exp(S/32)/Z[k], Z[k] = sum_{q>=k} exp(S/32)  (per-COLUMN denominator).
// Pass A (k_cstat) computes Z and folds 1/Z into V; pass B (k_ctx) recomputes S
// tile-wise and does PV. 1/32*log2e folded into Q at the QKV epilogue.
// Round 18: k_cvt_x + k_twb fused into one launch (k_prep, z=0 cvt / z=1-3 twb;
// they are input-independent and previously serialized). Rest = r17 best (100.5).

typedef __attribute__((ext_vector_type(8))) short short8;
typedef __attribute__((ext_vector_type(4))) float floatx4;
typedef __attribute__((ext_vector_type(16))) float floatx16;

#define SS 2048
#define DIN 1024
#define DOUT 1024
#define NH 16
#define HD 64
#define QSCALE 0.04508422002778011f  // (1/32) * log2(e)

#define MFMA16(a,b,c) __builtin_amdgcn_mfma_f32_16x16x32_bf16((a),(b),(c),0,0,0)
#define MFMA32(a,b,c) __builtin_amdgcn_mfma_f32_32x32x16_bf16((a),(b),(c),0,0,0)
#define EXP2F(x) __builtin_amdgcn_exp2f(x)
#define SBAR() __builtin_amdgcn_s_barrier()
#define WAITV0() asm volatile("s_waitcnt vmcnt(0)" ::: "memory")
#define WAITV4() asm volatile("s_waitcnt vmcnt(4)" ::: "memory")
#define WAITV8() asm volatile("s_waitcnt vmcnt(8)" ::: "memory")

__device__ __forceinline__ void gl_lds16(const void* g, void* l) {
  __builtin_amdgcn_global_load_lds((const __attribute__((address_space(1))) void*)g,
                                   (__attribute__((address_space(3))) void*)l, 16, 0, 0);
}

// Stage an 8-row chunk `c` of a [*][64] bf16 tile (global row stride `stride` elems)
// into LDS at lds + c*512, linear dest. XOR-swizzle applied on the GLOBAL source
// slot so that LDS[r][slot s] holds global slot s^(r&7).
__device__ __forceinline__ void stage64(const __hip_bfloat16* __restrict__ src, int stride,
                                        __hip_bfloat16* lds, int c, int l) {
  int r = c * 8 + (l >> 3);
  int cc = ((l & 7) ^ ((l >> 3) & 7)) * 8;
  gl_lds16(src + (size_t)r * stride + cc, lds + c * 512);
}

// 16x16x32 fragment from a [*][64] swizzled tile: row `row`, k-slot ks*4+(l>>4).
__device__ __forceinline__ short8 frag64(const __hip_bfloat16* lds, int row, int ks, int l) {
  return *(const short8*)&lds[row * 64 + (((ks * 4 + (l >> 4)) ^ (row & 7)) * 8)];
}

// 32x32x16 fragment: row `row` (0..63), 16-wide k-chunk `subk` (0..3), elems
// k = subk*16 + (l>>5)*8 + 0..7.
__device__ __forceinline__ short8 frag32(const __hip_bfloat16* lds, int row, int subk, int l) {
  return *(const short8*)&lds[row * 64 + (((subk * 2 + (l >> 5)) ^ (row & 7)) * 8)];
}

// ---- fused prep: z=0 convert x fp32->bf16 (16 elems/thread); z=1..3 transpose
// + convert Wq/Wk/Wv [k][c] fp32 -> Wt [c][k] bf16. Grid (32,32,4), 256 thr. ----
__global__ __launch_bounds__(256) void k_prep(
    const float* __restrict__ x, const float* __restrict__ Wq,
    const float* __restrict__ Wk, const float* __restrict__ Wv,
    __hip_bfloat16* __restrict__ xb,
    __hip_bfloat16* __restrict__ wtq, __hip_bfloat16* __restrict__ wtk,
    __hip_bfloat16* __restrict__ wtv) {
  const int tid = threadIdx.x;
  if (blockIdx.z == 0) {
    size_t base = (((size_t)blockIdx.y * 32 + blockIdx.x) * 256 + tid) * 16;
#pragma unroll
    for (int half = 0; half < 2; ++half) {
      size_t i = base + half * 8;
      float4 v0 = *(const float4*)(x + i);
      float4 v1 = *(const float4*)(x + i + 4);
      union { __hip_bfloat16 h[8]; short8 s; } u;
      u.h[0] = __float2bfloat16(v0.x); u.h[1] = __float2bfloat16(v0.y);
      u.h[2] = __float2bfloat16(v0.z); u.h[3] = __float2bfloat16(v0.w);
      u.h[4] = __float2bfloat16(v1.x); u.h[5] = __float2bfloat16(v1.y);
      u.h[6] = __float2bfloat16(v1.z); u.h[7] = __float2bfloat16(v1.w);
      *(short8*)(xb + i) = u.s;
    }
    return;
  }
  const float* W; __hip_bfloat16* Wt;
  if (blockIdx.z == 1)      { W = Wq; Wt = wtq; }
  else if (blockIdx.z == 2) { W = Wk; Wt = wtk; }
  else                      { W = Wv; Wt = wtv; }
  __shared__ float t[32][33];
  int tx = tid & 31, ty = tid >> 5;   // 32 x 8
  int k0 = blockIdx.y * 32, c0 = blockIdx.x * 32;
#pragma unroll
  for (int i = 0; i < 4; ++i)
    t[ty + 8*i][tx] = W[(size_t)(k0 + ty + 8*i) * DOUT + c0 + tx];
  __syncthreads();
#pragma unroll
  for (int i = 0; i < 4; ++i)
    Wt[(size_t)(c0 + ty + 8*i) * DIN + k0 + tx] = __float2bfloat16(t[tx][ty + 8*i]);
}

// ---- QKV GEMM, BK=64, double-buffered, swizzled LDS, counted-vmcnt pipeline,
// XCD-chunked tile swizzle. q (z=0, pre-scaled by QSCALE), k (z=1): [b][h][s][d];
// v (z=2): [b][h][d][s]. ----
__global__ __launch_bounds__(256) void k_qkv(
    const __hip_bfloat16* __restrict__ xb,
    const __hip_bfloat16* __restrict__ wq, const __hip_bfloat16* __restrict__ wk,
    const __hip_bfloat16* __restrict__ wv,
    __hip_bfloat16* __restrict__ qb, __hip_bfloat16* __restrict__ kb,
    __hip_bfloat16* __restrict__ vb) {
  __shared__ __hip_bfloat16 smem[32768];  // A0|A1|B0|B1, 8192 elems each (64KB)

  const __hip_bfloat16* wt; __hip_bfloat16* outp;
  if (blockIdx.z == 0)      { wt = wq; outp = qb; }
  else if (blockIdx.z == 1) { wt = wk; outp = kb; }
  else                      { wt = wv; outp = vb; }

  // XCD-chunked swizzle (T1): XCD = lin%8 owns 32 contiguous tiles = 4 row-
  // panels x all 8 col-tiles -> per-XCD L2 set = 1MB A + 2MB B < 4MB.
  const int lin = blockIdx.y * 8 + blockIdx.x;   // 0..255
  const int nl = (lin & 7) * 32 + (lin >> 3);
  const int row0 = (nl >> 3) * 128, col0 = (nl & 7) * 128;

  const int tid = threadIdx.x, w = tid >> 6, l = tid & 63;
  const int mw = (w >> 1) * 64, nw = (w & 1) * 64;

  const floatx4 fz = {0.f, 0.f, 0.f, 0.f};
  floatx4 acc[4][4];
#pragma unroll
  for (int m = 0; m < 4; ++m)
#pragma unroll
    for (int n = 0; n < 4; ++n) acc[m][n] = fz;

#pragma unroll
  for (int i = 0; i < 4; ++i) {
    stage64(xb + (size_t)row0 * DIN, DIN, smem, w*4+i, l);
    stage64(wt + (size_t)col0 * DIN, DIN, smem + 16384, w*4+i, l);
  }

  for (int kt = 0; kt < 16; ++kt) {
    int cur = kt & 1;
    __hip_bfloat16* Ac = smem + cur * 8192;
    __hip_bfloat16* Bc = smem + 16384 + cur * 8192;
    if (kt < 15) {
      int kk = (kt + 1) * 64;
      __hip_bfloat16* An = smem + (cur ^ 1) * 8192;
      __hip_bfloat16* Bn = smem + 16384 + (cur ^ 1) * 8192;
#pragma unroll
      for (int i = 0; i < 4; ++i) {
        stage64(xb + (size_t)row0 * DIN + kk, DIN, An, w*4+i, l);
        stage64(wt + (size_t)col0 * DIN + kk, DIN, Bn, w*4+i, l);
      }
      WAITV8();   // own loads for tile kt done; kt+1's 8 stay in flight
    } else {
      WAITV0();
    }
    SBAR();       // all waves' loads for tile kt landed
    short8 a[4][2], b[4][2];
#pragma unroll
    for (int m = 0; m < 4; ++m)
#pragma unroll
      for (int ks = 0; ks < 2; ++ks)
        a[m][ks] = frag64(Ac, mw + m*16 + (l & 15), ks, l);
#pragma unroll
    for (int n = 0; n < 4; ++n)
#pragma unroll
      for (int ks = 0; ks < 2; ++ks)
        b[n][ks] = frag64(Bc, nw + n*16 + (l & 15), ks, l);
#pragma unroll
    for (int ks = 0; ks < 2; ++ks)
#pragma unroll
      for (int m = 0; m < 4; ++m)
#pragma unroll
        for (int n = 0; n < 4; ++n)
          acc[m][n] = MFMA16(a[m][ks], b[n][ks], acc[m][n]);
    SBAR();       // reads of buf[cur] done before next iter's issue overwrites it
  }

  int bb2 = row0 >> 11, sbase = row0 & (SS - 1);
  if (blockIdx.z == 2) {
    // V: transpose through LDS (padded stride 136), then 16B coalesced stores.
    __hip_bfloat16* Vt2 = smem;
#pragma unroll
    for (int m = 0; m < 4; ++m)
#pragma unroll
      for (int n = 0; n < 4; ++n)
#pragma unroll
        for (int r4 = 0; r4 < 4; ++r4) {
          int r = mw + m*16 + ((l >> 4) << 2) + r4;
          int c = nw + n*16 + (l & 15);
          Vt2[c * 136 + r] = __float2bfloat16(acc[m][n][r4]);
        }
    __syncthreads();
#pragma unroll
    for (int i = 0; i < 8; ++i) {
      int drow = (tid >> 4) + i * 16;
      int scol = (tid & 15) * 8;
      int colg = col0 + drow, hh = colg >> 6, d = colg & 63;
      *(short8*)(outp + (((size_t)bb2 * NH + hh) * HD + d) * SS + sbase + scol) =
          *(const short8*)&Vt2[drow * 136 + scol];
    }
  } else {
    // Q/K: repack through LDS row-major [128][136], then 16B coalesced stores.
    float sc = (blockIdx.z == 0) ? QSCALE : 1.0f;
    __hip_bfloat16* T2 = smem;
#pragma unroll
    for (int m = 0; m < 4; ++m)
#pragma unroll
      for (int n = 0; n < 4; ++n)
#pragma unroll
        for (int r4 = 0; r4 < 4; ++r4) {
          int r = mw + m*16 + ((l >> 4) << 2) + r4;   // s-index in tile
          int c = nw + n*16 + (l & 15);               // d/head-col in tile
          T2[r * 136 + c] = __float2bfloat16(acc[m][n][r4] * sc);
        }
    __syncthreads();
#pragma unroll
    for (int i = 0; i < 8; ++i) {
      int r = (tid >> 4) + i * 16;          // 0..127 row (s)
      int c = (tid & 15) * 8;               // 0..120 col (d)
      int colg = col0 + c, hh = colg >> 6, d = colg & 63;
      *(short8*)(outp + (((size_t)bb2 * NH + hh) * SS + sbase + r) * HD + d) =
          *(const short8*)&T2[r * 136 + c];
    }
  }
}

// ---- pass A: Z[k] = sum_{q>=k} exp2(S'), then scale V columns by 1/Z in place.
// One j (64 k-columns) per block; grid (32 bh, 32 j), 3 blocks/CU co-resident. ----
__global__ __launch_bounds__(256) void k_cstat(const __hip_bfloat16* __restrict__ qb,
                                               const __hip_bfloat16* __restrict__ kb,
                                               __hip_bfloat16* __restrict__ vtb) {
  __shared__ __hip_bfloat16 smem[20480];  // Kt 4096 | Qt0 8192 | Qt1 8192 (40KB)
  __shared__ float red[4][64];
  __shared__ float zl[64];
  __hip_bfloat16* Kt = smem;
  const int bh = blockIdx.x;
  const int j = blockIdx.y;
  const int tid = threadIdx.x, w = tid >> 6, l = tid & 63;
  const int k0 = j * 64;
  const int t0 = j >> 1, niter = 16 - t0;

#pragma unroll
  for (int i = 0; i < 2; ++i)
    stage64(kb + ((size_t)bh * SS + k0) * HD, HD, Kt, w*2+i, l);
#pragma unroll
  for (int i = 0; i < 4; ++i)
    stage64(qb + ((size_t)bh * SS + (t0 << 7)) * HD, HD, smem + 4096, w*4+i, l);

  short8 kf[4][2];
  float csum[4] = {0.f, 0.f, 0.f, 0.f};
  for (int it = 0; it < niter; ++it) {
    int cur = it & 1;
    __hip_bfloat16* Qc = smem + 4096 + cur * 8192;
    int q0 = (t0 + it) << 7;
    if (it + 1 < niter) {
      __hip_bfloat16* Qn = smem + 4096 + (cur ^ 1) * 8192;
#pragma unroll
      for (int i = 0; i < 4; ++i)
        stage64(qb + ((size_t)bh * SS + q0 + 128) * HD, HD, Qn, w*4+i, l);
      WAITV4();   // K + Q(it) done; Q(it+1)'s 4 in flight
    } else {
      WAITV0();
    }
    SBAR();
    if (it == 0) {
#pragma unroll
      for (int n = 0; n < 4; ++n)
#pragma unroll
        for (int ks = 0; ks < 2; ++ks)
          kf[n][ks] = frag64(Kt, n*16 + (l & 15), ks, l);
    }
    int qw = q0 + w * 32;
    if (qw + 31 >= k0) {
      short8 qa[2][2];
#pragma unroll
      for (int mm = 0; mm < 2; ++mm)
#pragma unroll
        for (int ks = 0; ks < 2; ++ks)
          qa[mm][ks] = frag64(Qc, w*32 + mm*16 + (l & 15), ks, l);
      floatx4 s[2][4];
#pragma unroll
      for (int mm = 0; mm < 2; ++mm)
#pragma unroll
        for (int n = 0; n < 4; ++n) {
          floatx4 t = {0.f, 0.f, 0.f, 0.f};
#pragma unroll
          for (int ks = 0; ks < 2; ++ks) t = MFMA16(qa[mm][ks], kf[n][ks], t);
          s[mm][n] = t;
        }
      bool dia = (k0 + 63 > qw);
#pragma unroll
      for (int mm = 0; mm < 2; ++mm)
#pragma unroll
        for (int n = 0; n < 4; ++n)
#pragma unroll
          for (int r4 = 0; r4 < 4; ++r4) {
            float e = EXP2F(s[mm][n][r4]);
            if (dia) {
              int q = qw + mm*16 + ((l >> 4) << 2) + r4;
              int k = k0 + n*16 + (l & 15);
              if (k > q) e = 0.f;
            }
            csum[n] += e;
          }
    }
    SBAR();
  }

#pragma unroll
  for (int n = 0; n < 4; ++n) {
    csum[n] += __shfl_xor(csum[n], 16);
    csum[n] += __shfl_xor(csum[n], 32);
    if (l < 16) red[w][n*16 + l] = csum[n];
  }
  __syncthreads();
  if (tid < 64)
    zl[tid] = 1.0f / (red[0][tid] + red[1][tid] + red[2][tid] + red[3][tid]);
  __syncthreads();
  // scale vtb columns [k0, k0+64) by 1/Z (in place; disjoint per block)
#pragma unroll
  for (int i = 0; i < 4; ++i) {
    int d = (tid >> 4) + i * 16;
    int c = (tid & 15) * 4;
    size_t base = ((size_t)bh * HD + d) * SS + k0 + c;
    short4 v = *(const short4*)(vtb + base);
    __hip_bfloat16* hp = (__hip_bfloat16*)&v;
#pragma unroll
    for (int jv = 0; jv < 4; ++jv)
      hp[jv] = __float2bfloat16(__bfloat162float(hp[jv]) * zl[c + jv]);
    *(short4*)(vtb + base) = v;
  }
}

// ---- pass B: ctx[q,:] = sum_{k<=q} exp2(S') * Vs[k,:]  (Vs has 1/Z folded).
// K-SPLIT x2: 512 blocks x 8 waves (512 thr), 64KB LDS -> 2 independent
// blocks/CU = 4 waves/SIMD from 2 unaligned barrier groups (r13 win).
// Block i: bh = i&31, tb = (i<256) ? 15-(i>>5) : (i-256)>>5 (CU pairs big+small,
// per-CU load balanced: sum = 17 iters). Wave w: row-group g = w&3 (rows
// Q0+g+4c), k-half s = w>>2 (tiles s, s+2, ...). Private K/V dbuf per half:
// smem + s*16384 [K0|K1|V0|V1 x 4096]. Single acc[2], 4-deep QK chain.
__global__ __launch_bounds__(512, 4) void k_ctx(const __hip_bfloat16* __restrict__ qb,
                                                const __hip_bfloat16* __restrict__ kb,
                                                const __hip_bfloat16* __restrict__ vtb,
                                                float* __restrict__ outp) {
  __shared__ __hip_bfloat16 smem[32768];  // 64KB
  const int i = blockIdx.x;
  const int bh = i & 31, bb = bh >> 4, h = bh & 15;
  const int tb = (i < 256) ? (15 - (i >> 5)) : ((i - 256) >> 5);
  const int Q0 = tb * 128;
  const int tid = threadIdx.x, w = tid >> 6, l = tid & 63;
  const int g = w & 3, s = w >> 2;
  const int hi = l >> 5;
  const int qg = Q0 + g + 4 * (l & 31);   // lane's q-row (ST column c = l&31)
  const int nkt = 2 * (tb + 1);           // 64-wide k-tiles in causal range (even)
  const int nit = nkt >> 1;               // iterations per k-half
  __hip_bfloat16* qsm = smem + s * 16384; // half's region: K0|K1|V0|V1

  // Q fragments: lane q-row = qg, elems d = hc*16 + hi*8 .. +7. Drain vmcnt in
  // the prologue so loop's counted waits only see staging ops.
  short8 qf[4];
  {
    const __hip_bfloat16* qrow = qb + ((size_t)bh * SS + qg) * HD + hi * 8;
#pragma unroll
    for (int hc = 0; hc < 4; ++hc)
      qf[hc] = *(const short8*)(qrow + hc * 16);
  }
  asm volatile("" :: "v"(qf[0]), "v"(qf[1]), "v"(qf[2]), "v"(qf[3]));
  WAITV0();

  // stage half's first k-tile (index s): 2 K-chunks + 2 V-chunks per wave
  {
    int kn = s << 6;
#pragma unroll
    for (int ii = 0; ii < 2; ++ii) {
      stage64(kb + ((size_t)bh * SS + kn) * HD, HD, qsm, g*2+ii, l);
      stage64(vtb + (size_t)bh * HD * SS + kn, SS, qsm + 8192, g*2+ii, l);
    }
  }

  const floatx16 fz16 = {0,0,0,0,0,0,0,0,0,0,0,0,0,0,0,0};
  floatx16 acc[2];
  acc[0] = fz16; acc[1] = fz16;

  for (int it = 0; it < nit; ++it) {
    int cur = it & 1;
    __hip_bfloat16* Kc = qsm + cur * 4096;
    __hip_bfloat16* Vc = qsm + 8192 + cur * 4096;
    const int myk = s + 2 * it;
    const int nxt = myk + 2;
    if (nxt < nkt) {
      int kn = nxt << 6;
#pragma unroll
      for (int ii = 0; ii < 2; ++ii) {
        stage64(kb + ((size_t)bh * SS + kn) * HD, HD, qsm + (cur^1) * 4096, g*2+ii, l);
        stage64(vtb + (size_t)bh * HD * SS + kn, SS, qsm + 8192 + (cur^1) * 4096, g*2+ii, l);
      }
      WAITV4();   // tile myk's 4 landed; nxt's 4 stay in flight
    } else {
      WAITV0();
    }
    SBAR();       // buf[cur] fully populated

    {
      const int k0 = myk << 6;
      // ST halves: ST[k0+32H+roff][c], roff = (r&3)+8*(r>>2)+4*hi
      floatx16 st[2];
#pragma unroll
      for (int H = 0; H < 2; ++H) {
        floatx16 t = fz16;
#pragma unroll
        for (int hc = 0; hc < 4; ++hc)
          t = MFMA32(frag32(Kc, H*32 + (l & 31), hc, l), qf[hc], t);
        st[H] = t;
      }
      // exp2 + causal mask + pack to bf16 pairs: pk[H][m][pr] holds
      // k = k0 + 32H + 8m + 4hi + 2pr + {0,1}
      const bool dia = (k0 + 63 > Q0 + g);   // min q in wave = Q0 + g
      unsigned pk[2][4][2];
#pragma unroll
      for (int H = 0; H < 2; ++H)
#pragma unroll
        for (int m = 0; m < 4; ++m)
#pragma unroll
          for (int pr = 0; pr < 2; ++pr) {
            float e0 = EXP2F(st[H][m*4 + pr*2]);
            float e1 = EXP2F(st[H][m*4 + pr*2 + 1]);
            if (dia) {
              int kb0 = k0 + H*32 + m*8 + hi*4 + pr*2;
              if (kb0 > qg)     e0 = 0.f;
              if (kb0 + 1 > qg) e1 = 0.f;
            }
            pk[H][m][pr] = (unsigned)__bfloat16_as_ushort(__float2bfloat16(e0)) |
                           ((unsigned)__bfloat16_as_ushort(__float2bfloat16(e1)) << 16);
          }
      // PV: 4 k-chunks of 16; A-frag k = 16ks + hi*8 + 0..7.
#pragma unroll
      for (int ks = 0; ks < 4; ++ks) {
        const int H = ks >> 1, mb = (ks & 1) * 2;
        unsigned keep0 = hi ? pk[H][mb+1][0] : pk[H][mb][0];
        unsigned keep1 = hi ? pk[H][mb+1][1] : pk[H][mb][1];
        unsigned send0 = hi ? pk[H][mb][0]   : pk[H][mb+1][0];
        unsigned send1 = hi ? pk[H][mb][1]   : pk[H][mb+1][1];
        unsigned recv0 = (unsigned)__shfl_xor((int)send0, 32);
        unsigned recv1 = (unsigned)__shfl_xor((int)send1, 32);
        union { unsigned u[4]; short8 sv; } pa;
        pa.u[0] = hi ? recv0 : keep0;
        pa.u[1] = hi ? recv1 : keep1;
        pa.u[2] = hi ? keep0 : recv0;
        pa.u[3] = hi ? keep1 : recv1;
#pragma unroll
        for (int dn = 0; dn < 2; ++dn)
          acc[dn] = MFMA32(pa.sv, frag32(Vc, dn*32 + (l & 31), ks, l), acc[dn]);
      }
    }
    SBAR();       // reads of buf[cur] done before next iter overwrites it
  }

  // ---- reduce partials across the two k-halves ----
  float* fsm = (float*)smem;   // staging dead after final SBAR; 8192 floats used
  if (s == 1) {
    float* dst = fsm + g * 2048;
#pragma unroll
    for (int dn = 0; dn < 2; ++dn)
#pragma unroll
      for (int r = 0; r < 16; ++r)
        dst[(dn * 16 + r) * 64 + l] = acc[dn][r];
  }
  __syncthreads();
  if (s == 0) {
    const float* src = fsm + g * 2048;
#pragma unroll
    for (int dn = 0; dn < 2; ++dn)
#pragma unroll
      for (int r = 0; r < 16; ++r)
        acc[dn][r] += src[(dn * 16 + r) * 64 + l];
#pragma unroll
    for (int dn = 0; dn < 2; ++dn)
#pragma unroll
      for (int r = 0; r < 16; ++r) {
        int q = Q0 + g + 4 * ((r & 3) + 8*(r >> 2) + 4*hi);
        outp[((size_t)bb * SS + q) * DOUT + h * HD + dn*32 + (l & 31)] = acc[dn][r];
      }
  }
}

extern "C" void kernel_launch(void* const* d_in, const int* in_sizes, int n_in,
                              void* d_out, int out_size, void* d_ws, size_t ws_size,
                              hipStream_t stream) {
  const float* x  = (const float*)d_in[0];
  const float* Wq = (const float*)d_in[1];
  const float* Wk = (const float*)d_in[2];
  const float* Wv = (const float*)d_in[3];
  float* out = (float*)d_out;
  char* ws = (char*)d_ws;

  __hip_bfloat16* xb  = (__hip_bfloat16*)(ws);                   // 8 MB
  __hip_bfloat16* wtq = (__hip_bfloat16*)(ws + (8ull  << 20));   // 2 MB
  __hip_bfloat16* wtk = (__hip_bfloat16*)(ws + (10ull << 20));   // 2 MB
  __hip_bfloat16* wtv = (__hip_bfloat16*)(ws + (12ull << 20));   // 2 MB
  __hip_bfloat16* qb  = (__hip_bfloat16*)(ws + (14ull << 20));   // 8 MB [b][h][s][d], pre-scaled
  __hip_bfloat16* kb  = (__hip_bfloat16*)(ws + (22ull << 20));   // 8 MB [b][h][s][d]
  __hip_bfloat16* vtb = (__hip_bfloat16*)(ws + (30ull << 20));   // 8 MB [b][h][d][s], 1/Z folded

  k_prep<<<dim3(32, 32, 4), 256, 0, stream>>>(x, Wq, Wk, Wv, xb, wtq, wtk, wtv);
  k_qkv<<<dim3(8, 32, 3), 256, 0, stream>>>(xb, wtq, wtk, wtv, qb, kb, vtb);
  k_cstat<<<dim3(32, 32), 256, 0, stream>>>(qb, kb, vtb);
  k_ctx<<<dim3(512), 512, 0, stream>>>(qb, kb, vtb, out);
}